// Round 5
// baseline (342.064 us; speedup 1.0000x reference)
//
#include <hip/hip_runtime.h>
#include <hip/hip_bf16.h>
#include <float.h>

#define B_ 64
#define H_ 1024
#define S_ 1024
#define V_ 50257
#define L_ 3
#define G3H 3072      // 3*H
#define N_GATES 6144  // 2*3H fused gi|gh

typedef __attribute__((ext_vector_type(8))) short short8v;  // 8 bf16 (4 VGPRs)
typedef __attribute__((ext_vector_type(4))) float f32x4;    // MFMA accumulator

// round-to-nearest f32 -> bf16 bits
__device__ __forceinline__ ushort rnd_bf16(float x) {
    uint u = __float_as_uint(x);
    return (ushort)((u + 0x7fffu + ((u >> 16) & 1u)) >> 16);
}

// exact split x = hi + lo (hi = truncated bf16, lo = rounded residual)
__device__ __forceinline__ void split_bf16(float x, ushort& hi, ushort& lo) {
    uint u = __float_as_uint(x);
    uint h = u & 0xffff0000u;
    hi = (ushort)(h >> 16);
    float r = x - __uint_as_float(h);
    uint ur = __float_as_uint(r);
    lo = (ushort)((ur + 0x7fffu + ((ur >> 16) & 1u)) >> 16);
}

// ---------------------------------------------------------------------------
// Universal streaming bf16-MFMA GEMM (LDS-free): C[m][n] = sum_k A[m][k]*W[n][k]
// M=64 fixed. 128 threads = 2 waves; each wave owns 32 cols (2 16-col tiles).
// A read fp32, split hi+lo in-register (exact); W read fp32, rounded to bf16.
// Dual-A/W via Nhalf (col >= Nhalf uses A1/W1). Optional seq-gather on A0
// rows (embedding fusion). K-split via gridDim.y. Epilogue: direct store
// (+bias) if C != nullptr, else raw partials P[ks][64][Npad].
// mfma_f32_16x16x32_bf16: A lane l: row=l&15, k=(l>>4)*8+j; B: col=l&15,
// same k; D: col=l&15, row=(l>>4)*4+r.  (verified in R3/R4)
__global__ __launch_bounds__(128) void gemm_bf16_stream(
    const float* __restrict__ A0, const int* __restrict__ seq,
    const float* __restrict__ A1, int lda,
    const float* __restrict__ W0, const float* __restrict__ W1, int ldw,
    int Nhalf,
    const float* __restrict__ bias, float* __restrict__ C, int ldc,
    float* __restrict__ P, int Npad,
    int N, int K) {
    int tid = threadIdx.x;
    int w = tid >> 6, l = tid & 63;
    int lr = l & 15;  // row (A) / col (B) within 16-tile
    int lk = l >> 4;  // k-subgroup 0..3

    int n0 = blockIdx.x * 64 + w * 32;
    const float* A = A0;
    const float* W = W0;
    const int* sq = seq;
    int ncol0 = n0;
    if (n0 >= Nhalf) { A = A1; W = W1; ncol0 = n0 - Nhalf; sq = nullptr; }

    int gna = n0 + lr, gnb = n0 + 16 + lr;  // global output cols
    bool va = gna < N, vb = gnb < N;
    const float* Wa = W + (size_t)(ncol0 + lr) * ldw;
    const float* Wb = W + (size_t)(ncol0 + 16 + lr) * ldw;

    const float* Ar[4];
#pragma unroll
    for (int mt = 0; mt < 4; mt++) {
        int mr = mt * 16 + lr;
        Ar[mt] = sq ? (A + (size_t)sq[mr] * lda) : (A + (size_t)mr * lda);
    }

    f32x4 acc[4][2];
#pragma unroll
    for (int mt = 0; mt < 4; mt++)
#pragma unroll
        for (int nt = 0; nt < 2; nt++) acc[mt][nt] = (f32x4){0.f, 0.f, 0.f, 0.f};

    int kChunk = K / gridDim.y;
    int kBeg = blockIdx.y * kChunk, kEnd = kBeg + kChunk;

    const float4 fz = {0.f, 0.f, 0.f, 0.f};
    float4 wx0, wx1, wy0, wy1;  // W: tile a / tile b, 8 fp32 each
    float4 ax[4], ay[4];        // A: per m-tile, 8 fp32

    auto loadK = [&](int k0) {
        int kb = k0 + lk * 8;
        wx0 = va ? *(const float4*)&Wa[kb] : fz;
        wx1 = va ? *(const float4*)&Wa[kb + 4] : fz;
        wy0 = vb ? *(const float4*)&Wb[kb] : fz;
        wy1 = vb ? *(const float4*)&Wb[kb + 4] : fz;
#pragma unroll
        for (int mt = 0; mt < 4; mt++) {
            ax[mt] = *(const float4*)&Ar[mt][kb];
            ay[mt] = *(const float4*)&Ar[mt][kb + 4];
        }
    };

    union SV { short8v v; ushort u[8]; };

    loadK(kBeg);
    for (int k0 = kBeg; k0 < kEnd; k0 += 32) {
        // convert current regs -> fragments
        SV wfa, wfb;
        {
            const float* p0 = (const float*)&wx0;
            const float* p1 = (const float*)&wx1;
            const float* q0 = (const float*)&wy0;
            const float* q1 = (const float*)&wy1;
#pragma unroll
            for (int j = 0; j < 4; j++) {
                wfa.u[j] = rnd_bf16(p0[j]);
                wfa.u[j + 4] = rnd_bf16(p1[j]);
                wfb.u[j] = rnd_bf16(q0[j]);
                wfb.u[j + 4] = rnd_bf16(q1[j]);
            }
        }
        SV ah[4], al[4];
#pragma unroll
        for (int mt = 0; mt < 4; mt++) {
            const float* pa = (const float*)&ax[mt];
            const float* pb = (const float*)&ay[mt];
#pragma unroll
            for (int j = 0; j < 4; j++) {
                split_bf16(pa[j], ah[mt].u[j], al[mt].u[j]);
                split_bf16(pb[j], ah[mt].u[j + 4], al[mt].u[j + 4]);
            }
        }

        if (k0 + 32 < kEnd) loadK(k0 + 32);  // loads fly under the MFMAs

#pragma unroll
        for (int mt = 0; mt < 4; mt++) {
            acc[mt][0] = __builtin_amdgcn_mfma_f32_16x16x32_bf16(ah[mt].v, wfa.v, acc[mt][0], 0, 0, 0);
            acc[mt][0] = __builtin_amdgcn_mfma_f32_16x16x32_bf16(al[mt].v, wfa.v, acc[mt][0], 0, 0, 0);
            acc[mt][1] = __builtin_amdgcn_mfma_f32_16x16x32_bf16(ah[mt].v, wfb.v, acc[mt][1], 0, 0, 0);
            acc[mt][1] = __builtin_amdgcn_mfma_f32_16x16x32_bf16(al[mt].v, wfb.v, acc[mt][1], 0, 0, 0);
        }
    }

    if (C) {
        float ba = va ? (bias ? bias[gna] : 0.f) : 0.f;
        float bb = vb ? (bias ? bias[gnb] : 0.f) : 0.f;
#pragma unroll
        for (int mt = 0; mt < 4; mt++) {
#pragma unroll
            for (int r = 0; r < 4; r++) {
                int row = mt * 16 + lk * 4 + r;
                if (va) C[(size_t)row * ldc + gna] = acc[mt][0][r] + ba;
                if (vb) C[(size_t)row * ldc + gnb] = acc[mt][1][r] + bb;
            }
        }
    } else {
        float* Pp = P + (size_t)blockIdx.y * 64 * Npad;
#pragma unroll
        for (int mt = 0; mt < 4; mt++) {
#pragma unroll
            for (int r = 0; r < 4; r++) {
                int row = mt * 16 + lk * 4 + r;
                Pp[(size_t)row * Npad + gna] = acc[mt][0][r];
                Pp[(size_t)row * Npad + gnb] = acc[mt][1][r];
            }
        }
    }
}

// ---------------------------------------------------------------------------
// GRU gate combine: 4 K-split partials of fused [gi | gh] + biases -> h_out
__global__ __launch_bounds__(256) void gru_combine_k(
    const float* __restrict__ P, const float* __restrict__ b_ih,
    const float* __restrict__ b_hh, const float* __restrict__ hprev,
    float* __restrict__ hout) {
    int idx = blockIdx.x * 256 + threadIdx.x;  // 65536
    int b = idx >> 10, j = idx & 1023;
    const size_t stride = (size_t)64 * N_GATES;
    const float* rowp = P + (size_t)b * N_GATES;

    float ir = 0.f, iz = 0.f, in_ = 0.f, hr = 0.f, hz = 0.f, hn = 0.f;
#pragma unroll
    for (int kc = 0; kc < 4; kc++) {
        const float* p = rowp + kc * stride;
        ir += p[j];        iz += p[j + 1024];        in_ += p[j + 2048];
        hr += p[3072 + j]; hz += p[3072 + j + 1024]; hn += p[3072 + j + 2048];
    }
    ir += b_ih[j]; iz += b_ih[j + 1024]; in_ += b_ih[j + 2048];
    hr += b_hh[j]; hz += b_hh[j + 1024]; hn += b_hh[j + 2048];

    float r = 1.f / (1.f + __expf(-(ir + hr)));
    float z = 1.f / (1.f + __expf(-(iz + hz)));
    float n = tanhf(in_ + r * hn);
    float hp = hprev[idx];
    hout[idx] = (1.f - z) * n + z * hp;
}

// ---------------------------------------------------------------------------
// Fused attention pass 1: one enc read -> raw scores + online-softmax context
// partials. grid = 64 b * 16 sc; 4 waves/block, each wave owns 16 s rows.
__global__ __launch_bounds__(256) void attn_pass1(
    const float* __restrict__ rnn, const float* __restrict__ enc,
    float* __restrict__ scores, float* __restrict__ ctxPart,
    float* __restrict__ chunkMax) {
    __shared__ float lm[4];
    __shared__ float lc[4][1024];

    int bid = blockIdx.x;
    int b = bid >> 4, scv = bid & 15;
    int tid = threadIdx.x;
    int w = tid >> 6, lane = tid & 63;

    const float4* rr = (const float4*)(rnn + (size_t)b * H_);
    float4 r0 = rr[0 * 64 + lane], r1 = rr[1 * 64 + lane];
    float4 r2 = rr[2 * 64 + lane], r3 = rr[3 * 64 + lane];

    float m = -FLT_MAX;
    float4 c0 = {0, 0, 0, 0}, c1 = {0, 0, 0, 0}, c2 = {0, 0, 0, 0}, c3 = {0, 0, 0, 0};

    int s0 = scv * 64 + w * 16;
    for (int si = 0; si < 16; si++) {
        int s = s0 + si;
        const float4* er = (const float4*)(enc + ((size_t)s * B_ + b) * H_);
        float4 e0 = er[0 * 64 + lane], e1 = er[1 * 64 + lane];
        float4 e2 = er[2 * 64 + lane], e3 = er[3 * 64 + lane];

        float d = e0.x * r0.x + e0.y * r0.y + e0.z * r0.z + e0.w * r0.w;
        d += e1.x * r1.x + e1.y * r1.y + e1.z * r1.z + e1.w * r1.w;
        d += e2.x * r2.x + e2.y * r2.y + e2.z * r2.z + e2.w * r2.w;
        d += e3.x * r3.x + e3.y * r3.y + e3.z * r3.z + e3.w * r3.w;
#pragma unroll
        for (int off = 32; off; off >>= 1) d += __shfl_xor(d, off, 64);
        if (lane == 0) scores[(size_t)b * S_ + s] = d;

        if (d > m) {  // wave-uniform (d identical on all lanes)
            float scale = __expf(m - d);
            c0.x *= scale; c0.y *= scale; c0.z *= scale; c0.w *= scale;
            c1.x *= scale; c1.y *= scale; c1.z *= scale; c1.w *= scale;
            c2.x *= scale; c2.y *= scale; c2.z *= scale; c2.w *= scale;
            c3.x *= scale; c3.y *= scale; c3.z *= scale; c3.w *= scale;
            m = d;
        }
        float p = __expf(d - m);
        c0.x += p * e0.x; c0.y += p * e0.y; c0.z += p * e0.z; c0.w += p * e0.w;
        c1.x += p * e1.x; c1.y += p * e1.y; c1.z += p * e1.z; c1.w += p * e1.w;
        c2.x += p * e2.x; c2.y += p * e2.y; c2.z += p * e2.z; c2.w += p * e2.w;
        c3.x += p * e3.x; c3.y += p * e3.y; c3.z += p * e3.z; c3.w += p * e3.w;
    }

    if (lane == 0) lm[w] = m;
    __syncthreads();
    float M = fmaxf(fmaxf(lm[0], lm[1]), fmaxf(lm[2], lm[3]));
    float sw = __expf(m - M);
    float4* lw = (float4*)&lc[w][0];
    float4 t;
    t.x = c0.x * sw; t.y = c0.y * sw; t.z = c0.z * sw; t.w = c0.w * sw; lw[0 * 64 + lane] = t;
    t.x = c1.x * sw; t.y = c1.y * sw; t.z = c1.z * sw; t.w = c1.w * sw; lw[1 * 64 + lane] = t;
    t.x = c2.x * sw; t.y = c2.y * sw; t.z = c2.z * sw; t.w = c2.w * sw; lw[2 * 64 + lane] = t;
    t.x = c3.x * sw; t.y = c3.y * sw; t.z = c3.z * sw; t.w = c3.w * sw; lw[3 * 64 + lane] = t;
    __syncthreads();

    float4 s4 = *(const float4*)&lc[0][tid * 4];
    float4 a1 = *(const float4*)&lc[1][tid * 4];
    float4 a2 = *(const float4*)&lc[2][tid * 4];
    float4 a3 = *(const float4*)&lc[3][tid * 4];
    s4.x += a1.x + a2.x + a3.x; s4.y += a1.y + a2.y + a3.y;
    s4.z += a1.z + a2.z + a3.z; s4.w += a1.w + a2.w + a3.w;
    *(float4*)&ctxPart[(size_t)bid * H_ + tid * 4] = s4;
    if (tid == 0) chunkMax[bid] = M;
}

// ---------------------------------------------------------------------------
// Attention pass 2 (per b): global softmax -> attn output, rescale+sum chunk
// contexts, assemble concat_in = [rnn | ctx].
__global__ __launch_bounds__(256) void attn_pass2(
    const float* __restrict__ scores, const float* __restrict__ chunkMax,
    const float* __restrict__ ctxPart, const float* __restrict__ rnn,
    float* __restrict__ attn, float* __restrict__ concat_in) {
    __shared__ float red[256];
    int b = blockIdx.x, tid = threadIdx.x;

    float v[4];
#pragma unroll
    for (int q = 0; q < 4; q++) v[q] = scores[(size_t)b * S_ + q * 256 + tid];
    float mx = fmaxf(fmaxf(v[0], v[1]), fmaxf(v[2], v[3]));
    red[tid] = mx; __syncthreads();
    for (int s = 128; s; s >>= 1) {
        if (tid < s) red[tid] = fmaxf(red[tid], red[tid + s]);
        __syncthreads();
    }
    float M = red[0]; __syncthreads();
    float e[4], sum = 0.f;
#pragma unroll
    for (int q = 0; q < 4; q++) { e[q] = __expf(v[q] - M); sum += e[q]; }
    red[tid] = sum; __syncthreads();
    for (int s = 128; s; s >>= 1) {
        if (tid < s) red[tid] += red[tid + s];
        __syncthreads();
    }
    float inv = 1.f / red[0];
#pragma unroll
    for (int q = 0; q < 4; q++) attn[(size_t)b * S_ + q * 256 + tid] = e[q] * inv;

    float4 acc = {0, 0, 0, 0};
#pragma unroll
    for (int c = 0; c < 16; c++) {
        float scl = __expf(chunkMax[b * 16 + c] - M);
        float4 part = *(const float4*)&ctxPart[((size_t)b * 16 + c) * H_ + tid * 4];
        acc.x += scl * part.x; acc.y += scl * part.y;
        acc.z += scl * part.z; acc.w += scl * part.w;
    }
    acc.x *= inv; acc.y *= inv; acc.z *= inv; acc.w *= inv;
    *(float4*)&concat_in[(size_t)b * 2048 + 1024 + tid * 4] = acc;
    *(float4*)&concat_in[(size_t)b * 2048 + tid * 4] =
        *(const float4*)&rnn[(size_t)b * H_ + tid * 4];
}

// ---------------------------------------------------------------------------
// Concat combine: sum 8 K-split partials + bias, tanh -> concat_out (fp32)
__global__ __launch_bounds__(256) void concat_combine_k(const float* __restrict__ P,
                                                        const float* __restrict__ bias,
                                                        float* __restrict__ out) {
    int idx = blockIdx.x * 256 + threadIdx.x;  // 65536
    int b = idx >> 10, h = idx & 1023;
    float s = 0.f;
#pragma unroll
    for (int kc = 0; kc < 8; kc++) s += P[(size_t)kc * 65536 + (size_t)b * H_ + h];
    out[idx] = tanhf(s + bias[h]);
}

// ---------------------------------------------------------------------------
extern "C" void kernel_launch(void* const* d_in, const int* in_sizes, int n_in,
                              void* d_out, int out_size, void* d_ws, size_t ws_size,
                              hipStream_t stream) {
    const int* seq = (const int*)d_in[0];
    const float* last_hidden = (const float*)d_in[1];
    const float* enc = (const float*)d_in[2];
    const float* emb = (const float*)d_in[3];
    const float* w_ih = (const float*)d_in[4];
    const float* w_hh = (const float*)d_in[5];
    const float* b_ih = (const float*)d_in[6];
    const float* b_hh = (const float*)d_in[7];
    const float* concat_w = (const float*)d_in[8];
    const float* concat_b = (const float*)d_in[9];
    const float* out_w = (const float*)d_in[10];
    const float* out_b = (const float*)d_in[11];

    float* out = (float*)d_out;                           // (B,V)
    float* out_hidden = out + (size_t)B_ * V_;            // (L,B,H)
    float* out_attn = out_hidden + (size_t)L_ * B_ * H_;  // (B,1,S)

    float* ws = (float*)d_ws;
    float* gatesP = ws;                    // 4*64*6144 = 1572864
    float* scores = gatesP + 1572864;      // 65536
    float* chunkMax = scores + 65536;      // 1024
    float* ctxPart = chunkMax + 1024;      // 1048576
    float* concat_in = ctxPart + 1048576;  // 131072
    float* concatP = concat_in + 131072;   // 524288
    float* concat_out = concatP + 524288;  // 65536

    // 1+2. GRU layers (layer 0 fuses the embedding gather)
    for (int l = 0; l < L_; l++) {
        const float* xl = (l == 0) ? emb : out_hidden + (size_t)(l - 1) * B_ * H_;
        const int* sq = (l == 0) ? seq : nullptr;
        const float* hl = last_hidden + (size_t)l * B_ * H_;
        gemm_bf16_stream<<<dim3(N_GATES / 64, 4), 128, 0, stream>>>(
            xl, sq, hl, H_,
            w_ih + (size_t)l * G3H * H_, w_hh + (size_t)l * G3H * H_, H_, G3H,
            nullptr, nullptr, 0, gatesP, N_GATES, N_GATES, H_);
        gru_combine_k<<<256, 256, 0, stream>>>(gatesP, b_ih + (size_t)l * G3H,
                                               b_hh + (size_t)l * G3H, hl,
                                               out_hidden + (size_t)l * B_ * H_);
    }
    const float* rnn = out_hidden + (size_t)2 * B_ * H_;

    // 3. Fused attention (single enc pass) + combine/assemble
    attn_pass1<<<1024, 256, 0, stream>>>(rnn, enc, scores, ctxPart, chunkMax);
    attn_pass2<<<64, 256, 0, stream>>>(scores, chunkMax, ctxPart, rnn,
                                       out_attn, concat_in);

    // 4. Concat GEMM (K=2048, 8-way K-split) + tanh combine
    gemm_bf16_stream<<<dim3(16, 8), 128, 0, stream>>>(
        concat_in, nullptr, concat_in, 2048, concat_w, concat_w, 2048, 1 << 30,
        nullptr, nullptr, 0, concatP, H_, H_, 2048);
    concat_combine_k<<<256, 256, 0, stream>>>(concatP, concat_b, concat_out);

    // 5. Output GEMM: direct store with bias
    gemm_bf16_stream<<<dim3(786, 1), 128, 0, stream>>>(
        concat_out, nullptr, nullptr, H_, out_w, nullptr, H_, 1 << 30,
        out_b, out, V_, nullptr, 0, V_, H_);
}

// Round 6
// 267.878 us; speedup vs baseline: 1.2769x; 1.2769x over previous
//
#include <hip/hip_runtime.h>
#include <hip/hip_bf16.h>
#include <float.h>

#define B_ 64
#define H_ 1024
#define S_ 1024
#define V_ 50257
#define VPAD 50304   // V padded to multiple of 128
#define L_ 3
#define G3H 3072      // 3*H
#define N_GATES 6144  // 2*3H fused gi|gh

typedef __attribute__((ext_vector_type(8))) short short8v;  // 8 bf16 (4 VGPRs)
typedef __attribute__((ext_vector_type(4))) float f32x4;    // MFMA accumulator

// round-to-nearest f32 -> bf16 bits
__device__ __forceinline__ ushort rnd_bf16(float x) {
    uint u = __float_as_uint(x);
    return (ushort)((u + 0x7fffu + ((u >> 16) & 1u)) >> 16);
}

// exact split x = hi + lo (hi = truncated bf16, lo = rounded residual)
__device__ __forceinline__ void split_bf16(float x, ushort& hi, ushort& lo) {
    uint u = __float_as_uint(x);
    uint h = u & 0xffff0000u;
    hi = (ushort)(h >> 16);
    float r = x - __uint_as_float(h);
    uint ur = __float_as_uint(r);
    lo = (ushort)((ur + 0x7fffu + ((ur >> 16) & 1u)) >> 16);
}

// LDS XOR swizzle for fp32 GEMMs: permute 16B chunks within a row.
__device__ __forceinline__ int swzi(int kk, int m) {
    return (((m >> 2) ^ ((kk >> 2) & 7)) << 2) | (m & 3);
}

// ---------------------------------------------------------------------------
// Embedding gather: x0[b][h] = emb[seq[b]][h]
__global__ __launch_bounds__(256) void embed_k(const int* __restrict__ seq,
                                               const float* __restrict__ emb,
                                               float* __restrict__ x0) {
    int idx = blockIdx.x * 256 + threadIdx.x;  // 65536 total
    int b = idx >> 10, h = idx & 1023;
    x0[idx] = emb[(size_t)seq[b] * H_ + h];
}

// ---------------------------------------------------------------------------
// Generic M=64 fp32 GEMM (GRU gates + concat): C[m][n] = sum_k A[m][k]*W[n][k]
// Tile 64x64, KT=32, swizzled LDS, K-split partials to Cpart[kc][m][n].
__global__ __launch_bounds__(256) void gemm_m64(
    const float* __restrict__ A0, const float* __restrict__ A1, int lda,
    const float* __restrict__ W0, const float* __restrict__ W1, int ldw,
    int Nhalf, float* __restrict__ Cpart, int N, int K) {
    __shared__ float As[32 * 68];
    __shared__ float Ws[32 * 68];

    int n0 = blockIdx.x * 64;
    const float* A = A0;
    const float* W = W0;
    int ncol0 = n0;
    if (n0 >= Nhalf) { A = A1; W = W1; ncol0 = n0 - Nhalf; }

    int tid = threadIdx.x;
    int tx = tid & 15, ty = tid >> 4;
    int row = tid >> 3;  // 0..31
    int cg = tid & 7;    // k group of 4

    float acc[4][4] = {};

    int kChunk = K / gridDim.y;
    int k0b = blockIdx.y * kChunk;

    for (int k0 = k0b; k0 < k0b + kChunk; k0 += 32) {
        float4 a0 = *(const float4*)&A[(size_t)row * lda + k0 + cg * 4];
        float4 a1 = *(const float4*)&A[(size_t)(row + 32) * lda + k0 + cg * 4];
        float4 w0 = *(const float4*)&W[(size_t)(ncol0 + row) * ldw + k0 + cg * 4];
        float4 w1 = *(const float4*)&W[(size_t)(ncol0 + row + 32) * ldw + k0 + cg * 4];
        const float* fa0 = (const float*)&a0;
        const float* fa1 = (const float*)&a1;
        const float* fw0 = (const float*)&w0;
        const float* fw1 = (const float*)&w1;
#pragma unroll
        for (int j = 0; j < 4; j++) {
            int kk = cg * 4 + j;
            As[kk * 68 + swzi(kk, row)] = fa0[j];
            As[kk * 68 + swzi(kk, row + 32)] = fa1[j];
            Ws[kk * 68 + swzi(kk, row)] = fw0[j];
            Ws[kk * 68 + swzi(kk, row + 32)] = fw1[j];
        }
        __syncthreads();
#pragma unroll
        for (int kk = 0; kk < 32; kk++) {
            int cgk = (kk >> 2) & 7;
            float4 av = *(const float4*)&As[kk * 68 + ((ty ^ cgk) << 2)];
            float4 wv = *(const float4*)&Ws[kk * 68 + ((tx ^ cgk) << 2)];
            acc[0][0] += av.x * wv.x; acc[0][1] += av.x * wv.y;
            acc[0][2] += av.x * wv.z; acc[0][3] += av.x * wv.w;
            acc[1][0] += av.y * wv.x; acc[1][1] += av.y * wv.y;
            acc[1][2] += av.y * wv.z; acc[1][3] += av.y * wv.w;
            acc[2][0] += av.z * wv.x; acc[2][1] += av.z * wv.y;
            acc[2][2] += av.z * wv.z; acc[2][3] += av.z * wv.w;
            acc[3][0] += av.w * wv.x; acc[3][1] += av.w * wv.y;
            acc[3][2] += av.w * wv.z; acc[3][3] += av.w * wv.w;
        }
        __syncthreads();
    }

    float* P = Cpart + (size_t)blockIdx.y * 64 * N;
#pragma unroll
    for (int i = 0; i < 4; i++) {
        int m = ty * 4 + i;
#pragma unroll
        for (int j = 0; j < 4; j++) {
            int n = n0 + tx * 4 + j;
            P[(size_t)m * N + n] = acc[i][j];
        }
    }
}

// ---------------------------------------------------------------------------
// GRU gate combine: 4 K-split partials of fused [gi | gh] + biases -> h_out
__global__ __launch_bounds__(256) void gru_combine_k(
    const float* __restrict__ P, const float* __restrict__ b_ih,
    const float* __restrict__ b_hh, const float* __restrict__ hprev,
    float* __restrict__ hout) {
    int idx = blockIdx.x * 256 + threadIdx.x;  // 65536
    int b = idx >> 10, j = idx & 1023;
    const size_t stride = (size_t)64 * N_GATES;
    const float* rowp = P + (size_t)b * N_GATES;

    float ir = 0.f, iz = 0.f, in_ = 0.f, hr = 0.f, hz = 0.f, hn = 0.f;
#pragma unroll
    for (int kc = 0; kc < 4; kc++) {
        const float* p = rowp + kc * stride;
        ir += p[j];        iz += p[j + 1024];        in_ += p[j + 2048];
        hr += p[3072 + j]; hz += p[3072 + j + 1024]; hn += p[3072 + j + 2048];
    }
    ir += b_ih[j]; iz += b_ih[j + 1024]; in_ += b_ih[j + 2048];
    hr += b_hh[j]; hz += b_hh[j + 1024]; hn += b_hh[j + 2048];

    float r = 1.f / (1.f + __expf(-(ir + hr)));
    float z = 1.f / (1.f + __expf(-(iz + hz)));
    float n = tanhf(in_ + r * hn);
    float hp = hprev[idx];
    hout[idx] = (1.f - z) * n + z * hp;
}

// ---------------------------------------------------------------------------
// Fused attention pass 1: one enc read -> raw scores + online-softmax context
// partials. grid = 64 b * 16 sc; 4 waves/block, each wave owns 16 s rows.
__global__ __launch_bounds__(256) void attn_pass1(
    const float* __restrict__ rnn, const float* __restrict__ enc,
    float* __restrict__ scores, float* __restrict__ ctxPart,
    float* __restrict__ chunkMax) {
    __shared__ float lm[4];
    __shared__ float lc[4][1024];

    int bid = blockIdx.x;
    int b = bid >> 4, scv = bid & 15;
    int tid = threadIdx.x;
    int w = tid >> 6, lane = tid & 63;

    const float4* rr = (const float4*)(rnn + (size_t)b * H_);
    float4 r0 = rr[0 * 64 + lane], r1 = rr[1 * 64 + lane];
    float4 r2 = rr[2 * 64 + lane], r3 = rr[3 * 64 + lane];

    float m = -FLT_MAX;
    float4 c0 = {0, 0, 0, 0}, c1 = {0, 0, 0, 0}, c2 = {0, 0, 0, 0}, c3 = {0, 0, 0, 0};

    int s0 = scv * 64 + w * 16;
    for (int si = 0; si < 16; si++) {
        int s = s0 + si;
        const float4* er = (const float4*)(enc + ((size_t)s * B_ + b) * H_);
        float4 e0 = er[0 * 64 + lane], e1 = er[1 * 64 + lane];
        float4 e2 = er[2 * 64 + lane], e3 = er[3 * 64 + lane];

        float d = e0.x * r0.x + e0.y * r0.y + e0.z * r0.z + e0.w * r0.w;
        d += e1.x * r1.x + e1.y * r1.y + e1.z * r1.z + e1.w * r1.w;
        d += e2.x * r2.x + e2.y * r2.y + e2.z * r2.z + e2.w * r2.w;
        d += e3.x * r3.x + e3.y * r3.y + e3.z * r3.z + e3.w * r3.w;
#pragma unroll
        for (int off = 32; off; off >>= 1) d += __shfl_xor(d, off, 64);
        if (lane == 0) scores[(size_t)b * S_ + s] = d;

        if (d > m) {  // wave-uniform (d identical on all lanes)
            float scale = __expf(m - d);
            c0.x *= scale; c0.y *= scale; c0.z *= scale; c0.w *= scale;
            c1.x *= scale; c1.y *= scale; c1.z *= scale; c1.w *= scale;
            c2.x *= scale; c2.y *= scale; c2.z *= scale; c2.w *= scale;
            c3.x *= scale; c3.y *= scale; c3.z *= scale; c3.w *= scale;
            m = d;
        }
        float p = __expf(d - m);
        c0.x += p * e0.x; c0.y += p * e0.y; c0.z += p * e0.z; c0.w += p * e0.w;
        c1.x += p * e1.x; c1.y += p * e1.y; c1.z += p * e1.z; c1.w += p * e1.w;
        c2.x += p * e2.x; c2.y += p * e2.y; c2.z += p * e2.z; c2.w += p * e2.w;
        c3.x += p * e3.x; c3.y += p * e3.y; c3.z += p * e3.z; c3.w += p * e3.w;
    }

    if (lane == 0) lm[w] = m;
    __syncthreads();
    float M = fmaxf(fmaxf(lm[0], lm[1]), fmaxf(lm[2], lm[3]));
    float sw = __expf(m - M);
    float4* lw = (float4*)&lc[w][0];
    float4 t;
    t.x = c0.x * sw; t.y = c0.y * sw; t.z = c0.z * sw; t.w = c0.w * sw; lw[0 * 64 + lane] = t;
    t.x = c1.x * sw; t.y = c1.y * sw; t.z = c1.z * sw; t.w = c1.w * sw; lw[1 * 64 + lane] = t;
    t.x = c2.x * sw; t.y = c2.y * sw; t.z = c2.z * sw; t.w = c2.w * sw; lw[2 * 64 + lane] = t;
    t.x = c3.x * sw; t.y = c3.y * sw; t.z = c3.z * sw; t.w = c3.w * sw; lw[3 * 64 + lane] = t;
    __syncthreads();

    float4 s4 = *(const float4*)&lc[0][tid * 4];
    float4 a1 = *(const float4*)&lc[1][tid * 4];
    float4 a2 = *(const float4*)&lc[2][tid * 4];
    float4 a3 = *(const float4*)&lc[3][tid * 4];
    s4.x += a1.x + a2.x + a3.x; s4.y += a1.y + a2.y + a3.y;
    s4.z += a1.z + a2.z + a3.z; s4.w += a1.w + a2.w + a3.w;
    *(float4*)&ctxPart[(size_t)bid * H_ + tid * 4] = s4;
    if (tid == 0) chunkMax[bid] = M;
}

// ---------------------------------------------------------------------------
// Attention pass 2 (per b): global softmax -> attn output, rescale+sum chunk
// contexts, assemble concat_in = [rnn | ctx].
__global__ __launch_bounds__(256) void attn_pass2(
    const float* __restrict__ scores, const float* __restrict__ chunkMax,
    const float* __restrict__ ctxPart, const float* __restrict__ rnn,
    float* __restrict__ attn, float* __restrict__ concat_in) {
    __shared__ float red[256];
    int b = blockIdx.x, tid = threadIdx.x;

    float v[4];
#pragma unroll
    for (int q = 0; q < 4; q++) v[q] = scores[(size_t)b * S_ + q * 256 + tid];
    float mx = fmaxf(fmaxf(v[0], v[1]), fmaxf(v[2], v[3]));
    red[tid] = mx; __syncthreads();
    for (int s = 128; s; s >>= 1) {
        if (tid < s) red[tid] = fmaxf(red[tid], red[tid + s]);
        __syncthreads();
    }
    float M = red[0]; __syncthreads();
    float e[4], sum = 0.f;
#pragma unroll
    for (int q = 0; q < 4; q++) { e[q] = __expf(v[q] - M); sum += e[q]; }
    red[tid] = sum; __syncthreads();
    for (int s = 128; s; s >>= 1) {
        if (tid < s) red[tid] += red[tid + s];
        __syncthreads();
    }
    float inv = 1.f / red[0];
#pragma unroll
    for (int q = 0; q < 4; q++) attn[(size_t)b * S_ + q * 256 + tid] = e[q] * inv;

    float4 acc = {0, 0, 0, 0};
#pragma unroll
    for (int c = 0; c < 16; c++) {
        float scl = __expf(chunkMax[b * 16 + c] - M);
        float4 part = *(const float4*)&ctxPart[((size_t)b * 16 + c) * H_ + tid * 4];
        acc.x += scl * part.x; acc.y += scl * part.y;
        acc.z += scl * part.z; acc.w += scl * part.w;
    }
    acc.x *= inv; acc.y *= inv; acc.z *= inv; acc.w *= inv;
    *(float4*)&concat_in[(size_t)b * 2048 + 1024 + tid * 4] = acc;
    *(float4*)&concat_in[(size_t)b * 2048 + tid * 4] =
        *(const float4*)&rnn[(size_t)b * H_ + tid * 4];
}

// ---------------------------------------------------------------------------
// Concat combine: sum 8 K-split partials + bias, tanh; emit exact bf16
// hi/lo split of the result for the MFMA output GEMM.
__global__ __launch_bounds__(256) void concat_combine_k(const float* __restrict__ P,
                                                        const float* __restrict__ bias,
                                                        ushort* __restrict__ Ahi,
                                                        ushort* __restrict__ Alo) {
    int idx = blockIdx.x * 256 + threadIdx.x;  // 65536
    int b = idx >> 10, h = idx & 1023;
    float s = 0.f;
#pragma unroll
    for (int kc = 0; kc < 8; kc++) s += P[(size_t)kc * 65536 + (size_t)b * H_ + h];
    float v = tanhf(s + bias[h]);
    ushort hi, lo;
    split_bf16(v, hi, lo);
    Ahi[idx] = hi;
    Alo[idx] = lo;
}

// ---------------------------------------------------------------------------
// Output GEMM via bf16 MFMA, LDS-free streaming, 4 waves/block, K-split 2,
// 2-stage register pipeline (W prefetched a full iteration = 2 k-steps ahead).
// P[ks][64][VPAD] = (Ahi+Alo)[64][1024] x bf16(W)[V][1024]^T  (raw partials)
__global__ __launch_bounds__(256) void gemm_out_bf16(
    const ushort* __restrict__ Ahi, const ushort* __restrict__ Alo,
    const float* __restrict__ W, float* __restrict__ P) {
    int tid = threadIdx.x;
    int w = tid >> 6, l = tid & 63;
    int lr = l & 15;  // row (A) / col (B) within 16-tile
    int lk = l >> 4;  // k-subgroup (0..3)

    int n0 = blockIdx.x * 128 + w * 32;
    int na = n0 + lr, nb = n0 + 16 + lr;       // always < VPAD
    bool va = na < V_, vb = nb < V_;
    const float* Wa = W + (size_t)(va ? na : 0) * H_;  // clamp OOB rows to row 0
    const float* Wb = W + (size_t)(vb ? nb : 0) * H_;

    const int kBeg = blockIdx.y * 512, kEnd = kBeg + 512;

    f32x4 acc[4][2];
#pragma unroll
    for (int mt = 0; mt < 4; mt++)
#pragma unroll
        for (int nt = 0; nt < 2; nt++) acc[mt][nt] = (f32x4){0.f, 0.f, 0.f, 0.f};

    // pipeline registers: 2 stages
    float4 w0a0, w0a1, w0b0, w0b1;  // W stage 0 (fp32, 2 cols x 8)
    float4 w1a0, w1a1, w1b0, w1b1;  // W stage 1
    short8v a0h[4], a0l[4];         // A stage 0 (bf16 hi/lo per m-tile)
    short8v a1h[4], a1l[4];         // A stage 1

    auto loadW0 = [&](int k0) {
        int kb = min(k0, kEnd - 32) + lk * 8;
        w0a0 = *(const float4*)&Wa[kb]; w0a1 = *(const float4*)&Wa[kb + 4];
        w0b0 = *(const float4*)&Wb[kb]; w0b1 = *(const float4*)&Wb[kb + 4];
    };
    auto loadW1 = [&](int k0) {
        int kb = min(k0, kEnd - 32) + lk * 8;
        w1a0 = *(const float4*)&Wa[kb]; w1a1 = *(const float4*)&Wa[kb + 4];
        w1b0 = *(const float4*)&Wb[kb]; w1b1 = *(const float4*)&Wb[kb + 4];
    };
    auto loadA0 = [&](int k0) {
        int kb = min(k0, kEnd - 32) + lk * 8;
#pragma unroll
        for (int mt = 0; mt < 4; mt++) {
            int mr = mt * 16 + lr;
            a0h[mt] = *(const short8v*)&Ahi[(size_t)mr * H_ + kb];
            a0l[mt] = *(const short8v*)&Alo[(size_t)mr * H_ + kb];
        }
    };
    auto loadA1 = [&](int k0) {
        int kb = min(k0, kEnd - 32) + lk * 8;
#pragma unroll
        for (int mt = 0; mt < 4; mt++) {
            int mr = mt * 16 + lr;
            a1h[mt] = *(const short8v*)&Ahi[(size_t)mr * H_ + kb];
            a1l[mt] = *(const short8v*)&Alo[(size_t)mr * H_ + kb];
        }
    };

    union SV { short8v v; ushort u[8]; };

    loadW0(kBeg);
    loadW1(kBeg + 32);
    loadA0(kBeg);

    for (int k0 = kBeg; k0 < kEnd; k0 += 64) {
        // ---- stage 0: consume (k0) ----
        loadA1(k0 + 32);  // A for second half, L2-resident
        SV wfa, wfb;
        {
            const float* p0 = (const float*)&w0a0;
            const float* p1 = (const float*)&w0a1;
            const float* q0 = (const float*)&w0b0;
            const float* q1 = (const float*)&w0b1;
#pragma unroll
            for (int j = 0; j < 4; j++) {
                wfa.u[j] = rnd_bf16(p0[j]); wfa.u[j + 4] = rnd_bf16(p1[j]);
                wfb.u[j] = rnd_bf16(q0[j]); wfb.u[j + 4] = rnd_bf16(q1[j]);
            }
        }
        loadW0(k0 + 64);  // prefetch distance: 2 k-steps
#pragma unroll
        for (int mt = 0; mt < 4; mt++) {
            acc[mt][0] = __builtin_amdgcn_mfma_f32_16x16x32_bf16(a0h[mt], wfa.v, acc[mt][0], 0, 0, 0);
            acc[mt][0] = __builtin_amdgcn_mfma_f32_16x16x32_bf16(a0l[mt], wfa.v, acc[mt][0], 0, 0, 0);
            acc[mt][1] = __builtin_amdgcn_mfma_f32_16x16x32_bf16(a0h[mt], wfb.v, acc[mt][1], 0, 0, 0);
            acc[mt][1] = __builtin_amdgcn_mfma_f32_16x16x32_bf16(a0l[mt], wfb.v, acc[mt][1], 0, 0, 0);
        }

        // ---- stage 1: consume (k0+32) ----
        loadA0(k0 + 64);  // A for next iteration first half
        SV gfa, gfb;
        {
            const float* p0 = (const float*)&w1a0;
            const float* p1 = (const float*)&w1a1;
            const float* q0 = (const float*)&w1b0;
            const float* q1 = (const float*)&w1b1;
#pragma unroll
            for (int j = 0; j < 4; j++) {
                gfa.u[j] = rnd_bf16(p0[j]); gfa.u[j + 4] = rnd_bf16(p1[j]);
                gfb.u[j] = rnd_bf16(q0[j]); gfb.u[j + 4] = rnd_bf16(q1[j]);
            }
        }
        loadW1(k0 + 96);  // prefetch distance: 2 k-steps
#pragma unroll
        for (int mt = 0; mt < 4; mt++) {
            acc[mt][0] = __builtin_amdgcn_mfma_f32_16x16x32_bf16(a1h[mt], gfa.v, acc[mt][0], 0, 0, 0);
            acc[mt][0] = __builtin_amdgcn_mfma_f32_16x16x32_bf16(a1l[mt], gfa.v, acc[mt][0], 0, 0, 0);
            acc[mt][1] = __builtin_amdgcn_mfma_f32_16x16x32_bf16(a1h[mt], gfb.v, acc[mt][1], 0, 0, 0);
            acc[mt][1] = __builtin_amdgcn_mfma_f32_16x16x32_bf16(a1l[mt], gfb.v, acc[mt][1], 0, 0, 0);
        }
    }

    // raw partials; na/nb < VPAD so no masking needed here
    float* Pp = P + (size_t)blockIdx.y * 64 * VPAD;
#pragma unroll
    for (int mt = 0; mt < 4; mt++) {
#pragma unroll
        for (int r = 0; r < 4; r++) {
            int row = mt * 16 + lk * 4 + r;
            Pp[(size_t)row * VPAD + na] = acc[mt][0][r];
            Pp[(size_t)row * VPAD + nb] = acc[mt][1][r];
        }
    }
}

// ---------------------------------------------------------------------------
// Output combine: out[b][n] = P0[b][n] + P1[b][n] + bias[n]
__global__ __launch_bounds__(256) void out_combine_k(const float* __restrict__ P,
                                                     const float* __restrict__ bias,
                                                     float* __restrict__ out) {
    int n = blockIdx.x * 256 + threadIdx.x;
    int b = blockIdx.y;
    if (n < V_) {
        out[(size_t)b * V_ + n] = P[(size_t)b * VPAD + n] +
                                  P[(size_t)64 * VPAD + (size_t)b * VPAD + n] + bias[n];
    }
}

// ---------------------------------------------------------------------------
extern "C" void kernel_launch(void* const* d_in, const int* in_sizes, int n_in,
                              void* d_out, int out_size, void* d_ws, size_t ws_size,
                              hipStream_t stream) {
    const int* seq = (const int*)d_in[0];
    const float* last_hidden = (const float*)d_in[1];
    const float* enc = (const float*)d_in[2];
    const float* emb = (const float*)d_in[3];
    const float* w_ih = (const float*)d_in[4];
    const float* w_hh = (const float*)d_in[5];
    const float* b_ih = (const float*)d_in[6];
    const float* b_hh = (const float*)d_in[7];
    const float* concat_w = (const float*)d_in[8];
    const float* concat_b = (const float*)d_in[9];
    const float* out_w = (const float*)d_in[10];
    const float* out_b = (const float*)d_in[11];

    float* out = (float*)d_out;                           // (B,V)
    float* out_hidden = out + (size_t)B_ * V_;            // (L,B,H)
    float* out_attn = out_hidden + (size_t)L_ * B_ * H_;  // (B,1,S)

    float* ws = (float*)d_ws;
    float* x0 = ws;                        // 65536
    float* gatesP = x0 + 65536;            // 4*64*6144 = 1572864
    float* scores = gatesP + 1572864;      // 65536
    float* chunkMax = scores + 65536;      // 1024
    float* ctxPart = chunkMax + 1024;      // 1048576
    float* concat_in = ctxPart + 1048576;  // 131072
    float* concatP = concat_in + 131072;   // 524288
    ushort* Ahi = (ushort*)(concatP + 524288);  // 65536 ushort = 32768 floats
    ushort* Alo = Ahi + 65536;                  // 65536 ushort
    float* outP = (float*)(Alo + 65536);        // 2*64*50304 = 6438912 floats

    // 1. Embedding
    embed_k<<<256, 256, 0, stream>>>(seq, emb, x0);

    // 2. GRU layers
    for (int l = 0; l < L_; l++) {
        const float* xl = (l == 0) ? x0 : out_hidden + (size_t)(l - 1) * B_ * H_;
        const float* hl = last_hidden + (size_t)l * B_ * H_;
        gemm_m64<<<dim3(N_GATES / 64, 4), 256, 0, stream>>>(
            xl, hl, H_,
            w_ih + (size_t)l * G3H * H_, w_hh + (size_t)l * G3H * H_, H_, G3H,
            gatesP, N_GATES, H_);
        gru_combine_k<<<256, 256, 0, stream>>>(gatesP, b_ih + (size_t)l * G3H,
                                               b_hh + (size_t)l * G3H, hl,
                                               out_hidden + (size_t)l * B_ * H_);
    }
    const float* rnn = out_hidden + (size_t)2 * B_ * H_;

    // 3. Fused attention (single enc pass) + combine/assemble
    attn_pass1<<<1024, 256, 0, stream>>>(rnn, enc, scores, ctxPart, chunkMax);
    attn_pass2<<<64, 256, 0, stream>>>(scores, chunkMax, ctxPart, rnn,
                                       out_attn, concat_in);

    // 4. Concat GEMM (K=2048, 8-way K-split) + tanh combine (+ bf16 split)
    gemm_m64<<<dim3(16, 8), 256, 0, stream>>>(
        concat_in, concat_in, 2048, concat_w, concat_w, 2048, 1 << 30,
        concatP, H_, 2048);
    concat_combine_k<<<256, 256, 0, stream>>>(concatP, concat_b, Ahi, Alo);

    // 5. Output GEMM: 4 waves, K-split 2, pipelined streaming; then combine
    gemm_out_bf16<<<dim3((VPAD / 128), 2), 256, 0, stream>>>(Ahi, Alo, out_w, outP);
    out_combine_k<<<dim3((V_ + 255) / 256, 64), 256, 0, stream>>>(outP, out_b, out);
}